// Round 6
// baseline (362.865 us; speedup 1.0000x reference)
//
#include <hip/hip_runtime.h>
#include <math.h>

// CRITICAL: no FMA contraction — bit-replicating numpy's SSE float32 einsum.
#pragma clang fp contract(off)

typedef float f32x2 __attribute__((ext_vector_type(2)));

#define T_TOKENS 16384
#define HDIM 2048
#define NEXP 64
#define TOPK 6
#define SEQ 4096
#define TPB 32          // tokens per block
#define NTHR 256        // 4 waves
#define KC 64           // k-chunk
#define WS 68           // padded LDS stride for W tile (proven ~free, round 3)
#define LGS 65          // padded stride for logits/probs scratch

// Thread layout (256 thr):
//   le = tid&15        -> experts {le, le+16, le+32, le+48}
//   h  = (tid>>4)&1    -> SSE chain pair: h0 -> chains {0,1}, h1 -> chains {2,3}
//   tg = tid>>5 (0..7) -> tokens tg*4 .. tg*4+3
// numpy 16-block chain per SSE lane l: v = a0*b0 + (a1*b1 + (a2*b2 + (a3*b3 + v)))
// applied j = 3..0 with separate mul/add (contract off). Chains are independent;
// final hadd (v0+v1)+(v2+v3) is reproduced as h0-partial + h1-partial via LDS
// (validated bit-exact in round 4).
__global__ __launch_bounds__(NTHR, 4) void moe_gate_main(
    const float* __restrict__ x, const float* __restrict__ wgt,
    float* __restrict__ out, float* __restrict__ gacc)
{
    __shared__ float w_lds[NEXP * WS];    // 17408 B
    __shared__ float lg[TPB * LGS];       //  8320 B
    __shared__ float probs[TPB * LGS];    //  8320 B (aliases h1 partials pre-softmax)
    __shared__ float psum[4 * NEXP];      //  1024 B
    __shared__ int   cnt[NEXP];           //   256 B

    const int tid = threadIdx.x;
    const int bid = blockIdx.x;
    const int tb  = bid * TPB;
    const int b   = tb >> 12;             // /4096

    const int le = tid & 15;
    const int h  = (tid >> 4) & 1;
    const int tg = tid >> 5;              // 0..7
    const int t0 = tg * 4;

    // acc[je][tt]: one f32x2 = this thread's two SSE chains. 32 VGPRs.
    f32x2 acc[4][4];
    #pragma unroll
    for (int je = 0; je < 4; ++je)
        #pragma unroll
        for (int tt = 0; tt < 4; ++tt) { acc[je][tt].x = 0.f; acc[je][tt].y = 0.f; }

    const float* xb = x + (size_t)(tb + t0) * HDIM + 2 * h;

    for (int c = 0; c < HDIM / KC; ++c) {
        const int k0 = c * KC;
        __syncthreads();   // previous chunk's w readers done
        // ---- stage W chunk: 64 rows x 16 float4, 4 f4/thread (round-3 pattern)
        #pragma unroll
        for (int i = 0; i < 4; ++i) {
            int idx = i * NTHR + tid;
            int e = idx >> 4, c4 = idx & 15;
            float4 v = *reinterpret_cast<const float4*>(&wgt[e * HDIM + k0 + c4 * 4]);
            *reinterpret_cast<float4*>(&w_lds[e * WS + c4 * 4]) = v;
        }
        __syncthreads();

        #pragma unroll
        for (int b16 = 0; b16 < 4; ++b16) {
            const int kk = k0 + b16 * 16;
            // x fragments for this 16-block: global b64, 16 lanes broadcast,
            // h0/h1 merge to 16B. Hoisted -> ~16 outstanding vmem for latency.
            f32x2 xf[4][4];
            #pragma unroll
            for (int tt = 0; tt < 4; ++tt)
                #pragma unroll
                for (int j = 0; j < 4; ++j)
                    xf[tt][j] = *reinterpret_cast<const f32x2*>(
                        &xb[(size_t)tt * HDIM + kk + 4 * j]);
            // numpy's reversed chain: j = 3..0
            #pragma unroll
            for (int j = 3; j >= 0; --j) {
                f32x2 wf[4];
                #pragma unroll
                for (int je = 0; je < 4; ++je)
                    wf[je] = *reinterpret_cast<const f32x2*>(
                        &w_lds[(le + 16 * je) * WS + (kk - k0) + 4 * j + 2 * h]);
                #pragma unroll
                for (int je = 0; je < 4; ++je)
                    #pragma unroll
                    for (int tt = 0; tt < 4; ++tt) {
                        f32x2 p = wf[je] * xf[tt][j];   // v_pk_mul_f32 (or 2x v_mul)
                        acc[je][tt] = p + acc[je][tt];  // v_pk_add_f32 (or 2x v_add)
                    }
            }
        }
    }

    // ---- combine chain halves: (v0+v1) + (v2+v3)
    float* part1 = probs;                 // alias: dead before softmax writes
    if (h == 1) {
        #pragma unroll
        for (int je = 0; je < 4; ++je)
            #pragma unroll
            for (int tt = 0; tt < 4; ++tt)
                part1[(t0 + tt) * LGS + le + 16 * je] = acc[je][tt].x + acc[je][tt].y;
    }
    if (tid < NEXP) cnt[tid] = 0;
    __syncthreads();
    if (h == 0) {
        #pragma unroll
        for (int je = 0; je < 4; ++je)
            #pragma unroll
            for (int tt = 0; tt < 4; ++tt) {
                float p0 = acc[je][tt].x + acc[je][tt].y;
                lg[(t0 + tt) * LGS + le + 16 * je] =
                    p0 + part1[(t0 + tt) * LGS + le + 16 * je];
            }
    }
    __syncthreads();

    // ---- softmax per token (threads 0..31), fp32, numpy pairwise sum
    if (tid < TPB) {
        const int t = tid;
        float mx = lg[t * LGS];
        for (int e = 1; e < NEXP; ++e) { float v = lg[t * LGS + e]; if (v > mx) mx = v; }
        for (int e = 0; e < NEXP; ++e)
            probs[t * LGS + e] = expf(lg[t * LGS + e] - mx);
        float r[8];
        #pragma unroll
        for (int j = 0; j < 8; ++j) r[j] = probs[t * LGS + j];
        for (int i = 8; i < 64; i += 8)
            #pragma unroll
            for (int j = 0; j < 8; ++j) r[j] += probs[t * LGS + i + j];
        float S = ((r[0] + r[1]) + (r[2] + r[3])) + ((r[4] + r[5]) + (r[6] + r[7]));
        for (int e = 0; e < NEXP; ++e) probs[t * LGS + e] = probs[t * LGS + e] / S;
    }
    __syncthreads();

    // ---- partial per-expert prob sums (aux loss), all 256 threads
    {
        const int e = tid & 63, q = tid >> 6;
        float s = 0.f;
        for (int t = q * 8; t < q * 8 + 8; ++t) s += probs[t * LGS + e];
        psum[q * 64 + e] = s;
    }
    __syncthreads();

    if (tid < TPB) {
        // ---- top-6 on probs, strict > ascending scan (tie -> lowest index)
        const int t = tid;
        const int gt = tb + t;
        float pv[TOPK]; int pi[TOPK];
        for (int r = 0; r < TOPK; ++r) {
            float bv = -1.f; int be = 0;
            for (int e = 0; e < NEXP; ++e) {
                float v = probs[t * LGS + e];
                if (v > bv) { bv = v; be = e; }
            }
            probs[t * LGS + be] = -1.f;
            pv[r] = bv; pi[r] = be;
            atomicAdd(&cnt[be], 1);
        }
        float wsum = pv[0];
        #pragma unroll
        for (int r = 1; r < TOPK; ++r) wsum += pv[r];
        wsum += 1e-20f;
        #pragma unroll
        for (int r = 0; r < TOPK; ++r) {
            out[(size_t)gt * TOPK + r] = (float)pi[r];
            out[(size_t)T_TOKENS * TOPK + (size_t)gt * TOPK + r] = pv[r] / wsum;
        }
    } else if (tid >= 64 && tid < 128) {
        const int e = tid - 64;
        float s = psum[e] + psum[64 + e] + psum[128 + e] + psum[192 + e];
        atomicAdd(&gacc[b * 64 + e], s);
    }
    __syncthreads();
    if (tid < NEXP) {
        atomicAdd(&gacc[256 + b * 64 + tid], (float)cnt[tid]);
    }
}

// Finalize: aux = ALPHA * mean_b( sum_e (cnt*E/(S*K)) * (ssum/S) )
__global__ __launch_bounds__(256) void moe_gate_aux(
    const float* __restrict__ gacc, float* __restrict__ out)
{
    __shared__ float red[4];
    const int tid = threadIdx.x;
    float v = gacc[256 + tid] * gacc[tid];
    #pragma unroll
    for (int o = 32; o > 0; o >>= 1) v += __shfl_down(v, o, 64);
    if ((tid & 63) == 0) red[tid >> 6] = v;
    __syncthreads();
    if (tid == 0) {
        float tot = red[0] + red[1] + red[2] + red[3];
        const float scale = (64.0f / (4096.0f * 6.0f)) / 4096.0f;
        out[2 * T_TOKENS * TOPK] = 1e-3f * (tot * scale) * 0.25f;
    }
}

extern "C" void kernel_launch(void* const* d_in, const int* in_sizes, int n_in,
                              void* d_out, int out_size, void* d_ws, size_t ws_size,
                              hipStream_t stream) {
    const float* x   = (const float*)d_in[0];
    const float* wgt = (const float*)d_in[1];
    float* out  = (float*)d_out;
    float* gacc = (float*)d_ws;

    hipMemsetAsync(d_ws, 0, 512 * sizeof(float), stream);
    moe_gate_main<<<T_TOKENS / TPB, NTHR, 0, stream>>>(x, wgt, out, gacc);
    moe_gate_aux<<<1, 256, 0, stream>>>(gacc, out);
}